// Round 2
// baseline (14498.236 us; speedup 1.0000x reference)
//
#include <hip/hip_runtime.h>
#include <math.h>

#define T_STEPS 4096
#define HDIM    2048
#define KDIM    2048
#define NG      8192      // 4*H
#define CTR_STRIDE 16     // uints: one 64B line per counter
#define NREC    2048      // records per slot: one {h,tag} per h element

typedef unsigned long long ull;

// ---------------- init ----------------
// ctr[8] (64B apart): monotonic hint counters, seeded 32 (= "h0 published").
// recs[2][NREC]: tagged h records, 8B each: {lo: h bits, hi: tag}.
// tag convention: producer of step t writes tag t+1; consumer at step t
// expects tag t in its read slot. Slot 1 = h0 (tag 0); slot 0 = sentinel.
__global__ void init_ws4(const float* __restrict__ h0,
                         unsigned* __restrict__ ctr,    // [8*CTR_STRIDE]
                         uint2* __restrict__ recs) {    // [2][NREC]
    int g = blockIdx.x * blockDim.x + threadIdx.x;
    if (g < 8 * CTR_STRIDE) ctr[g] = ((g % CTR_STRIDE) == 0) ? 32u : 0u;
    int d = g - 8 * CTR_STRIDE;
    if (d >= 0 && d < 2 * NREC) {
        int slot = d >> 11;
        int r = d & (NREC - 1);
        uint2 v;
        if (slot == 1) {
            v.x = __float_as_uint(h0[r]);
            v.y = 0u;                      // tag 0 = "published by step -1"
        } else {
            v.x = 0u;
            v.y = 0xFFFFFFFFu;             // never matches any expected tag
        }
        recs[d] = v;
    }
}

// ---------------- Phase 1: Y = X @ Wi + bias (fp32 tiled GEMM) ----------------
__global__ __launch_bounds__(256) void gemm_xwi(
    const float* __restrict__ X, const float* __restrict__ Wi,
    const float* __restrict__ bias, float* __restrict__ Y)
{
    __shared__ float As[16][65];
    __shared__ __align__(16) float Bs[16][64];
    const int tid = threadIdx.x;
    const int m0 = blockIdx.y * 64;
    const int n0 = blockIdx.x * 64;
    const int tx4 = (tid & 15) * 4;
    const int ty4 = (tid >> 4) * 4;
    const int am = tid >> 2, ak = (tid & 3) * 4;
    const int bk = tid >> 4, bn = (tid & 15) * 4;

    float acc[4][4];
#pragma unroll
    for (int i = 0; i < 4; ++i)
#pragma unroll
        for (int j = 0; j < 4; ++j) acc[i][j] = 0.f;

    for (int kt = 0; kt < KDIM; kt += 16) {
        float4 av = *reinterpret_cast<const float4*>(&X[(size_t)(m0 + am) * KDIM + kt + ak]);
        float4 bv = *reinterpret_cast<const float4*>(&Wi[(size_t)(kt + bk) * NG + n0 + bn]);
        __syncthreads();
        As[ak + 0][am] = av.x; As[ak + 1][am] = av.y;
        As[ak + 2][am] = av.z; As[ak + 3][am] = av.w;
        *reinterpret_cast<float4*>(&Bs[bk][bn]) = bv;
        __syncthreads();
#pragma unroll
        for (int k = 0; k < 16; ++k) {
            float a0 = As[k][ty4 + 0], a1 = As[k][ty4 + 1];
            float a2 = As[k][ty4 + 2], a3 = As[k][ty4 + 3];
            float4 b4 = *reinterpret_cast<const float4*>(&Bs[k][tx4]);
            acc[0][0] = fmaf(a0, b4.x, acc[0][0]); acc[0][1] = fmaf(a0, b4.y, acc[0][1]);
            acc[0][2] = fmaf(a0, b4.z, acc[0][2]); acc[0][3] = fmaf(a0, b4.w, acc[0][3]);
            acc[1][0] = fmaf(a1, b4.x, acc[1][0]); acc[1][1] = fmaf(a1, b4.y, acc[1][1]);
            acc[1][2] = fmaf(a1, b4.z, acc[1][2]); acc[1][3] = fmaf(a1, b4.w, acc[1][3]);
            acc[2][0] = fmaf(a2, b4.x, acc[2][0]); acc[2][1] = fmaf(a2, b4.y, acc[2][1]);
            acc[2][2] = fmaf(a2, b4.z, acc[2][2]); acc[2][3] = fmaf(a2, b4.w, acc[2][3]);
            acc[3][0] = fmaf(a3, b4.x, acc[3][0]); acc[3][1] = fmaf(a3, b4.y, acc[3][1]);
            acc[3][2] = fmaf(a3, b4.z, acc[3][2]); acc[3][3] = fmaf(a3, b4.w, acc[3][3]);
        }
    }
    float4 bb = *reinterpret_cast<const float4*>(&bias[n0 + tx4]);
#pragma unroll
    for (int i = 0; i < 4; ++i) {
        float4 o;
        o.x = acc[i][0] + bb.x; o.y = acc[i][1] + bb.y;
        o.z = acc[i][2] + bb.z; o.w = acc[i][3] + bb.w;
        *reinterpret_cast<float4*>(&Y[(size_t)(m0 + ty4 + i) * NG + n0 + tx4]) = o;
    }
}

// ---------------- fast activations ----------------
__device__ __forceinline__ float fsigm(float x) { return 1.f / (1.f + __expf(-x)); }
__device__ __forceinline__ float ftanh(float x) {
    float ax = fabsf(x);
    float e  = __expf(2.f * ax);
    float t  = (e - 1.f) / (e + 1.f);
    t = (ax > 15.f) ? 1.f : t;
    return copysignf(t, x);
}

// ---------------- Phase 2: persistent recurrent kernel ----------------
// 256 blocks x 512 threads, cooperative, 1 block/CU.
// Publication: h goes out as eight self-validating 8B records
// {h, tag=t+1} via single global_store_dwordx2 sc0sc1 (naturally aligned
// 64-bit store = single-copy atomic -> data+tag arrive together). The
// counter atomicAdd is only a HINT, issued back-to-back with the stores
// with NO vmcnt release drain (-1 full MALL RTT ~0.4-0.5us per step off
// the critical chain). Consumers poll the 8 hint counters (2048 poll
// lanes chip-wide, no FETCH storm), then load records and VERIFY tags,
// retrying on staleness (rare: the record load samples the MALL at least
// one poll-RTT after the hint landed, and records were issued first).
// Lap safety (2 slots): block X stores slot t&1 at end of step t only
// after its top-of-step poll saw ctr >= 32*(t+1), i.e. every block
// finished step t-1 INCLUDING its increment, which in program order
// follows its verified-complete reads of slot t&1. The required ordering
// is increment-after-read (same-thread program order), not store
// visibility, so dropping the drain is safe. Stale tags (t-1 from the
// previous lap) simply cause a retry.
__global__ __launch_bounds__(512, 2) void lstm_persistent(
    const float* __restrict__ Y,     // [T][NG]
    const float* __restrict__ c0,
    const float* __restrict__ Wh,    // [K][NG]
    uint2* __restrict__ recs,        // [2][NREC] tagged h records
    unsigned* __restrict__ ctr,      // [8*CTR_STRIDE]
    float* __restrict__ out)         // [c_f][h_f][ys]
{
    const int b    = blockIdx.x;
    const int tid  = threadIdx.x;
    const int lane = tid & 63;
    const int w    = tid >> 6;       // 0..7
    const int gg   = w >> 1;
    const int hg   = w & 1;
    const int nbase = (gg << 11) + (b << 3) + (hg << 2);

    __shared__ __align__(16) float hlds[HDIM];   // 8 KiB staging
    __shared__ float gates[32];
    __shared__ float c_s[8];
    __shared__ float hlast[8];
    __shared__ unsigned ldsflag;

    // ---- load weight slice once, force register residency ----
    float4 wreg[32];
#pragma unroll
    for (int j = 0; j < 8; ++j)
#pragma unroll
        for (int m = 0; m < 4; ++m) {
            const size_t k = (size_t)(4 * lane + 256 * j + m);
            wreg[j * 4 + m] = *reinterpret_cast<const float4*>(&Wh[k * NG + nbase]);
        }
#pragma unroll
    for (int i = 0; i < 32; ++i) {
        asm volatile("" : "+v"(wreg[i].x), "+v"(wreg[i].y),
                          "+v"(wreg[i].z), "+v"(wreg[i].w));
    }

    if (tid < 8) c_s[tid] = c0[b * 8 + tid];
    if (tid == 0) ldsflag = 0xFFFFFFFFu;
    __syncthreads();

    for (int t = 0; t < T_STEPS; ++t) {
        const int rs = (t + 1) & 1;          // read slot (h input of step t)
        const unsigned target = 32u * (unsigned)(t + 1);

        // Y prefetch (hidden under the wait)
        float yv = 0.f;
        if (lane < 4) yv = Y[(size_t)t * NG + nbase + lane];

        // ---- hint detect: wave 0 polls 8 counters; others spin on LDS ----
        if (w == 0) {
            const unsigned* cp = ctr + (size_t)(lane & 7) * CTR_STRIDE;
            for (;;) {
                unsigned v = target;
                if (lane < 8)
                    v = __hip_atomic_load(cp, __ATOMIC_RELAXED, __HIP_MEMORY_SCOPE_SYSTEM);
                if (__all(v >= target)) break;
                __builtin_amdgcn_s_sleep(1);
            }
            if (lane == 0)
                __hip_atomic_store(&ldsflag, (unsigned)t, __ATOMIC_RELEASE,
                                   __HIP_MEMORY_SCOPE_WORKGROUP);
        } else {
            while (__hip_atomic_load(&ldsflag, __ATOMIC_ACQUIRE,
                                     __HIP_MEMORY_SCOPE_WORKGROUP) != (unsigned)t)
                __builtin_amdgcn_s_sleep(1);
        }

        // ---- tagged record load: 2x16B per thread (= 2x2 records),
        //      verify all 4 tags, retry if any stale ----
        {
            const uint2* rb = recs + (size_t)rs * NREC;
            const uint2* p0 = rb + 2 * tid;          // records 2t, 2t+1
            const uint2* p1 = rb + 1024 + 2 * tid;   // records 1024+2t, +1
            const unsigned expt = (unsigned)t;
            uint4 ra, rc;   // {h_a, tag_a, h_b, tag_b}
            for (;;) {
                asm volatile("global_load_dwordx4 %0, %2, off sc0 sc1\n\t"
                             "global_load_dwordx4 %1, %3, off sc0 sc1\n\t"
                             "s_waitcnt vmcnt(0)"
                             : "=&v"(ra), "=&v"(rc)
                             : "v"(p0), "v"(p1) : "memory");
                if (__all((ra.y == expt) & (ra.w == expt) &
                          (rc.y == expt) & (rc.w == expt))) break;
                __builtin_amdgcn_s_sleep(1);
            }
            float2 d0; d0.x = __uint_as_float(ra.x); d0.y = __uint_as_float(ra.z);
            float2 d1; d1.x = __uint_as_float(rc.x); d1.y = __uint_as_float(rc.z);
            *reinterpret_cast<float2*>(&hlds[2 * tid])        = d0;
            *reinterpret_cast<float2*>(&hlds[1024 + 2 * tid]) = d1;
        }
        __syncthreads();   // all of h staged

        // ---- 128 FMAs on register-resident weights ----
        float4 acc; acc.x = acc.y = acc.z = acc.w = 0.f;
#pragma unroll
        for (int j = 0; j < 8; ++j) {
            float4 h4 = reinterpret_cast<const float4*>(hlds)[lane + 64 * j];
            float4 w0 = wreg[4 * j + 0], w1 = wreg[4 * j + 1];
            float4 w2 = wreg[4 * j + 2], w3 = wreg[4 * j + 3];
            acc.x = fmaf(h4.x, w0.x, acc.x); acc.x = fmaf(h4.y, w1.x, acc.x);
            acc.x = fmaf(h4.z, w2.x, acc.x); acc.x = fmaf(h4.w, w3.x, acc.x);
            acc.y = fmaf(h4.x, w0.y, acc.y); acc.y = fmaf(h4.y, w1.y, acc.y);
            acc.y = fmaf(h4.z, w2.y, acc.y); acc.y = fmaf(h4.w, w3.y, acc.y);
            acc.z = fmaf(h4.x, w0.z, acc.z); acc.z = fmaf(h4.y, w1.z, acc.z);
            acc.z = fmaf(h4.z, w2.z, acc.z); acc.z = fmaf(h4.w, w3.z, acc.z);
            acc.w = fmaf(h4.x, w0.w, acc.w); acc.w = fmaf(h4.y, w1.w, acc.w);
            acc.w = fmaf(h4.z, w2.w, acc.w); acc.w = fmaf(h4.w, w3.w, acc.w);
        }
#pragma unroll
        for (int off = 32; off >= 1; off >>= 1) {
            acc.x += __shfl_xor(acc.x, off);
            acc.y += __shfl_xor(acc.y, off);
            acc.z += __shfl_xor(acc.z, off);
            acc.w += __shfl_xor(acc.w, off);
        }
        if (lane < 4) {
            float v = (lane == 0) ? acc.x : (lane == 1) ? acc.y
                    : (lane == 2) ? acc.z : acc.w;
            gates[gg * 8 + hg * 4 + lane] = v + yv;
        }
        __syncthreads();   // gates ready; all hlds reads of step t done

        // ---- epilogue: tagged 8B publish, NO release drain, hint add ----
        if (tid < 8) {
            float iv = gates[0 * 8 + tid];
            float fv = gates[1 * 8 + tid];
            float gv = gates[2 * 8 + tid];
            float ov = gates[3 * 8 + tid];
            float cn = fsigm(fv) * c_s[tid] + fsigm(iv) * ftanh(gv);
            float hn = fsigm(ov) * ftanh(cn);
            c_s[tid] = cn;
            hlast[tid] = hn;
            // {lo: h bits, hi: tag t+1} -> one 64b store, single-copy atomic
            ull rec = ((ull)(unsigned)(t + 1) << 32) | (ull)__float_as_uint(hn);
            uint2* dst = recs + (size_t)(t & 1) * NREC + b * 8 + tid;
            asm volatile("global_store_dwordx2 %0, %1, off sc0 sc1"
                         :: "v"(dst), "v"(rec) : "memory");
            if (tid == 0)
                __hip_atomic_fetch_add(ctr + (size_t)(b >> 5) * CTR_STRIDE, 1u,
                                       __ATOMIC_RELAXED, __HIP_MEMORY_SCOPE_SYSTEM);
            __builtin_nontemporal_store(hn, &out[2 * HDIM + (size_t)t * HDIM + b * 8 + tid]);
        }
    }

    if (tid < 8) {
        out[b * 8 + tid]        = c_s[tid];   // c_f
        out[HDIM + b * 8 + tid] = hlast[tid]; // h_f
    }
}

// ---------------- launch ----------------
extern "C" void kernel_launch(void* const* d_in, const int* in_sizes, int n_in,
                              void* d_out, int out_size, void* d_ws, size_t ws_size,
                              hipStream_t stream) {
    const float* x   = (const float*)d_in[0];
    const float* c0  = (const float*)d_in[1];
    const float* h0  = (const float*)d_in[2];
    const float* Wi  = (const float*)d_in[3];
    const float* Wh  = (const float*)d_in[4];
    const float* bia = (const float*)d_in[5];
    float* out = (float*)d_out;

    char* base = (char*)d_ws;
    float* Y = (float*)base;                                  // 128 MiB
    base += (size_t)T_STEPS * NG * sizeof(float);
    unsigned* ctr = (unsigned*)base;                          // 512 B
    base += 8 * CTR_STRIDE * sizeof(unsigned);
    uint2* recs = (uint2*)base;                               // 32 KiB

    const int initN = 8 * CTR_STRIDE + 2 * NREC;
    hipLaunchKernelGGL(init_ws4, dim3((initN + 511) / 512), dim3(512), 0, stream,
                       h0, ctr, recs);
    hipLaunchKernelGGL(gemm_xwi, dim3(NG / 64, T_STEPS / 64), dim3(256), 0, stream,
                       x, Wi, bia, Y);

    void* args[] = { (void*)&Y, (void*)&c0, (void*)&Wh,
                     (void*)&recs, (void*)&ctr, (void*)&out };
    (void)hipLaunchCooperativeKernel((const void*)lstm_persistent, dim3(256), dim3(512),
                                     args, 0, stream);
}

// Round 3
// 13861.761 us; speedup vs baseline: 1.0459x; 1.0459x over previous
//
#include <hip/hip_runtime.h>
#include <math.h>

#define T_STEPS 4096
#define HDIM    2048
#define KDIM    2048
#define NG      8192      // 4*H
#define CTR_STRIDE 16     // uints: one 64B line per counter
#define NREC    2048      // records per slot: one {h,tag} per h element

typedef unsigned long long ull;

// ---------------- init ----------------
// ctr[8] (64B apart): monotonic hint counters, seeded 32 (= "h0 published").
// recs[2][NREC]: tagged h records, 8B each: {lo: h bits, hi: tag}.
// tag convention: producer of step t writes tag t+1; consumer at step t
// expects tag t in its read slot. Slot 1 = h0 (tag 0); slot 0 = sentinel.
__global__ void init_ws4(const float* __restrict__ h0,
                         unsigned* __restrict__ ctr,    // [8*CTR_STRIDE]
                         uint2* __restrict__ recs) {    // [2][NREC]
    int g = blockIdx.x * blockDim.x + threadIdx.x;
    if (g < 8 * CTR_STRIDE) ctr[g] = ((g % CTR_STRIDE) == 0) ? 32u : 0u;
    int d = g - 8 * CTR_STRIDE;
    if (d >= 0 && d < 2 * NREC) {
        int slot = d >> 11;
        int r = d & (NREC - 1);
        uint2 v;
        if (slot == 1) {
            v.x = __float_as_uint(h0[r]);
            v.y = 0u;                      // tag 0 = "published by step -1"
        } else {
            v.x = 0u;
            v.y = 0xFFFFFFFFu;             // never matches any expected tag
        }
        recs[d] = v;
    }
}

// ---------------- Phase 1: Y = X @ Wi + bias (fp32 tiled GEMM) ----------------
__global__ __launch_bounds__(256) void gemm_xwi(
    const float* __restrict__ X, const float* __restrict__ Wi,
    const float* __restrict__ bias, float* __restrict__ Y)
{
    __shared__ float As[16][65];
    __shared__ __align__(16) float Bs[16][64];
    const int tid = threadIdx.x;
    const int m0 = blockIdx.y * 64;
    const int n0 = blockIdx.x * 64;
    const int tx4 = (tid & 15) * 4;
    const int ty4 = (tid >> 4) * 4;
    const int am = tid >> 2, ak = (tid & 3) * 4;
    const int bk = tid >> 4, bn = (tid & 15) * 4;

    float acc[4][4];
#pragma unroll
    for (int i = 0; i < 4; ++i)
#pragma unroll
        for (int j = 0; j < 4; ++j) acc[i][j] = 0.f;

    for (int kt = 0; kt < KDIM; kt += 16) {
        float4 av = *reinterpret_cast<const float4*>(&X[(size_t)(m0 + am) * KDIM + kt + ak]);
        float4 bv = *reinterpret_cast<const float4*>(&Wi[(size_t)(kt + bk) * NG + n0 + bn]);
        __syncthreads();
        As[ak + 0][am] = av.x; As[ak + 1][am] = av.y;
        As[ak + 2][am] = av.z; As[ak + 3][am] = av.w;
        *reinterpret_cast<float4*>(&Bs[bk][bn]) = bv;
        __syncthreads();
#pragma unroll
        for (int k = 0; k < 16; ++k) {
            float a0 = As[k][ty4 + 0], a1 = As[k][ty4 + 1];
            float a2 = As[k][ty4 + 2], a3 = As[k][ty4 + 3];
            float4 b4 = *reinterpret_cast<const float4*>(&Bs[k][tx4]);
            acc[0][0] = fmaf(a0, b4.x, acc[0][0]); acc[0][1] = fmaf(a0, b4.y, acc[0][1]);
            acc[0][2] = fmaf(a0, b4.z, acc[0][2]); acc[0][3] = fmaf(a0, b4.w, acc[0][3]);
            acc[1][0] = fmaf(a1, b4.x, acc[1][0]); acc[1][1] = fmaf(a1, b4.y, acc[1][1]);
            acc[1][2] = fmaf(a1, b4.z, acc[1][2]); acc[1][3] = fmaf(a1, b4.w, acc[1][3]);
            acc[2][0] = fmaf(a2, b4.x, acc[2][0]); acc[2][1] = fmaf(a2, b4.y, acc[2][1]);
            acc[2][2] = fmaf(a2, b4.z, acc[2][2]); acc[2][3] = fmaf(a2, b4.w, acc[2][3]);
            acc[3][0] = fmaf(a3, b4.x, acc[3][0]); acc[3][1] = fmaf(a3, b4.y, acc[3][1]);
            acc[3][2] = fmaf(a3, b4.z, acc[3][2]); acc[3][3] = fmaf(a3, b4.w, acc[3][3]);
        }
    }
    float4 bb = *reinterpret_cast<const float4*>(&bias[n0 + tx4]);
#pragma unroll
    for (int i = 0; i < 4; ++i) {
        float4 o;
        o.x = acc[i][0] + bb.x; o.y = acc[i][1] + bb.y;
        o.z = acc[i][2] + bb.z; o.w = acc[i][3] + bb.w;
        *reinterpret_cast<float4*>(&Y[(size_t)(m0 + ty4 + i) * NG + n0 + tx4]) = o;
    }
}

// ---------------- fast activations ----------------
__device__ __forceinline__ float fsigm(float x) { return 1.f / (1.f + __expf(-x)); }
__device__ __forceinline__ float ftanh(float x) {
    float ax = fabsf(x);
    float e  = __expf(2.f * ax);
    float t  = (e - 1.f) / (e + 1.f);
    t = (ax > 15.f) ? 1.f : t;
    return copysignf(t, x);
}

// ---------------- Phase 2: persistent recurrent kernel ----------------
// 256 blocks x 512 threads, cooperative, 1 block/CU.
//
// ROUND 3 change (isolated): register residency for wreg[32] (128 VGPRs).
// Round-2 counters showed VGPR_Count=84 -> the weight array was spilled
// and re-fetched (64 MB chip-wide per step) every one of the 4096 steps;
// that refetch (~2us at L2/MALL BW) WAS the step time. Cause:
// __launch_bounds__(512, 2) capped VGPRs at 128 (2-blocks/CU semantics).
// Fix: demand exactly 2 waves/EU (= the 1 block/CU we actually run) via
// amdgpu_waves_per_eu(2,2) -> VGPR budget 256 -> wreg + loop state fits.
//
// Publication protocol (unchanged from round 2): h goes out as eight
// self-validating 8B records {h, tag=t+1} via single global_store_dwordx2
// sc0sc1 (naturally aligned 64-bit store = single-copy atomic). Counter
// atomicAdd is a HINT with NO vmcnt release drain. Consumers poll the 8
// hint counters, then load records and VERIFY tags, retrying on stale.
// Lap safety: increment-after-read is same-thread program order. QED.
__global__ __launch_bounds__(512)
__attribute__((amdgpu_waves_per_eu(2, 2)))
void lstm_persistent(
    const float* __restrict__ Y,     // [T][NG]
    const float* __restrict__ c0,
    const float* __restrict__ Wh,    // [K][NG]
    uint2* __restrict__ recs,        // [2][NREC] tagged h records
    unsigned* __restrict__ ctr,      // [8*CTR_STRIDE]
    float* __restrict__ out)         // [c_f][h_f][ys]
{
    const int b    = blockIdx.x;
    const int tid  = threadIdx.x;
    const int lane = tid & 63;
    const int w    = tid >> 6;       // 0..7
    const int gg   = w >> 1;
    const int hg   = w & 1;
    const int nbase = (gg << 11) + (b << 3) + (hg << 2);

    __shared__ __align__(16) float hlds[HDIM];   // 8 KiB staging
    __shared__ float gates[32];
    __shared__ float c_s[8];
    __shared__ float hlast[8];
    __shared__ unsigned ldsflag;

    // ---- load weight slice once, force register residency ----
    float4 wreg[32];
#pragma unroll
    for (int j = 0; j < 8; ++j)
#pragma unroll
        for (int m = 0; m < 4; ++m) {
            const size_t k = (size_t)(4 * lane + 256 * j + m);
            wreg[j * 4 + m] = *reinterpret_cast<const float4*>(&Wh[k * NG + nbase]);
        }
#pragma unroll
    for (int i = 0; i < 32; ++i) {
        asm volatile("" : "+v"(wreg[i].x), "+v"(wreg[i].y),
                          "+v"(wreg[i].z), "+v"(wreg[i].w));
    }

    if (tid < 8) c_s[tid] = c0[b * 8 + tid];
    if (tid == 0) ldsflag = 0xFFFFFFFFu;
    __syncthreads();

    for (int t = 0; t < T_STEPS; ++t) {
        const int rs = (t + 1) & 1;          // read slot (h input of step t)
        const unsigned target = 32u * (unsigned)(t + 1);

        // Y prefetch (hidden under the wait)
        float yv = 0.f;
        if (lane < 4) yv = Y[(size_t)t * NG + nbase + lane];

        // ---- hint detect: wave 0 polls 8 counters; others spin on LDS ----
        if (w == 0) {
            const unsigned* cp = ctr + (size_t)(lane & 7) * CTR_STRIDE;
            for (;;) {
                unsigned v = target;
                if (lane < 8)
                    v = __hip_atomic_load(cp, __ATOMIC_RELAXED, __HIP_MEMORY_SCOPE_SYSTEM);
                if (__all(v >= target)) break;
                __builtin_amdgcn_s_sleep(1);
            }
            if (lane == 0)
                __hip_atomic_store(&ldsflag, (unsigned)t, __ATOMIC_RELEASE,
                                   __HIP_MEMORY_SCOPE_WORKGROUP);
        } else {
            while (__hip_atomic_load(&ldsflag, __ATOMIC_ACQUIRE,
                                     __HIP_MEMORY_SCOPE_WORKGROUP) != (unsigned)t)
                __builtin_amdgcn_s_sleep(1);
        }

        // ---- tagged record load: 2x16B per thread (= 2x2 records),
        //      verify all 4 tags, retry if any stale ----
        {
            const uint2* rb = recs + (size_t)rs * NREC;
            const uint2* p0 = rb + 2 * tid;          // records 2t, 2t+1
            const uint2* p1 = rb + 1024 + 2 * tid;   // records 1024+2t, +1
            const unsigned expt = (unsigned)t;
            uint4 ra, rc;   // {h_a, tag_a, h_b, tag_b}
            for (;;) {
                asm volatile("global_load_dwordx4 %0, %2, off sc0 sc1\n\t"
                             "global_load_dwordx4 %1, %3, off sc0 sc1\n\t"
                             "s_waitcnt vmcnt(0)"
                             : "=&v"(ra), "=&v"(rc)
                             : "v"(p0), "v"(p1) : "memory");
                if (__all((ra.y == expt) & (ra.w == expt) &
                          (rc.y == expt) & (rc.w == expt))) break;
                __builtin_amdgcn_s_sleep(1);
            }
            float2 d0; d0.x = __uint_as_float(ra.x); d0.y = __uint_as_float(ra.z);
            float2 d1; d1.x = __uint_as_float(rc.x); d1.y = __uint_as_float(rc.z);
            *reinterpret_cast<float2*>(&hlds[2 * tid])        = d0;
            *reinterpret_cast<float2*>(&hlds[1024 + 2 * tid]) = d1;
        }
        __syncthreads();   // all of h staged

        // ---- 128 FMAs on register-resident weights ----
        float4 acc; acc.x = acc.y = acc.z = acc.w = 0.f;
#pragma unroll
        for (int j = 0; j < 8; ++j) {
            float4 h4 = reinterpret_cast<const float4*>(hlds)[lane + 64 * j];
            float4 w0 = wreg[4 * j + 0], w1 = wreg[4 * j + 1];
            float4 w2 = wreg[4 * j + 2], w3 = wreg[4 * j + 3];
            acc.x = fmaf(h4.x, w0.x, acc.x); acc.x = fmaf(h4.y, w1.x, acc.x);
            acc.x = fmaf(h4.z, w2.x, acc.x); acc.x = fmaf(h4.w, w3.x, acc.x);
            acc.y = fmaf(h4.x, w0.y, acc.y); acc.y = fmaf(h4.y, w1.y, acc.y);
            acc.y = fmaf(h4.z, w2.y, acc.y); acc.y = fmaf(h4.w, w3.y, acc.y);
            acc.z = fmaf(h4.x, w0.z, acc.z); acc.z = fmaf(h4.y, w1.z, acc.z);
            acc.z = fmaf(h4.z, w2.z, acc.z); acc.z = fmaf(h4.w, w3.z, acc.z);
            acc.w = fmaf(h4.x, w0.w, acc.w); acc.w = fmaf(h4.y, w1.w, acc.w);
            acc.w = fmaf(h4.z, w2.w, acc.w); acc.w = fmaf(h4.w, w3.w, acc.w);
        }
#pragma unroll
        for (int off = 32; off >= 1; off >>= 1) {
            acc.x += __shfl_xor(acc.x, off);
            acc.y += __shfl_xor(acc.y, off);
            acc.z += __shfl_xor(acc.z, off);
            acc.w += __shfl_xor(acc.w, off);
        }
        if (lane < 4) {
            float v = (lane == 0) ? acc.x : (lane == 1) ? acc.y
                    : (lane == 2) ? acc.z : acc.w;
            gates[gg * 8 + hg * 4 + lane] = v + yv;
        }
        __syncthreads();   // gates ready; all hlds reads of step t done

        // ---- epilogue: tagged 8B publish, NO release drain, hint add ----
        if (tid < 8) {
            float iv = gates[0 * 8 + tid];
            float fv = gates[1 * 8 + tid];
            float gv = gates[2 * 8 + tid];
            float ov = gates[3 * 8 + tid];
            float cn = fsigm(fv) * c_s[tid] + fsigm(iv) * ftanh(gv);
            float hn = fsigm(ov) * ftanh(cn);
            c_s[tid] = cn;
            hlast[tid] = hn;
            // {lo: h bits, hi: tag t+1} -> one 64b store, single-copy atomic
            ull rec = ((ull)(unsigned)(t + 1) << 32) | (ull)__float_as_uint(hn);
            uint2* dst = recs + (size_t)(t & 1) * NREC + b * 8 + tid;
            asm volatile("global_store_dwordx2 %0, %1, off sc0 sc1"
                         :: "v"(dst), "v"(rec) : "memory");
            if (tid == 0)
                __hip_atomic_fetch_add(ctr + (size_t)(b >> 5) * CTR_STRIDE, 1u,
                                       __ATOMIC_RELAXED, __HIP_MEMORY_SCOPE_SYSTEM);
            __builtin_nontemporal_store(hn, &out[2 * HDIM + (size_t)t * HDIM + b * 8 + tid]);
        }
    }

    if (tid < 8) {
        out[b * 8 + tid]        = c_s[tid];   // c_f
        out[HDIM + b * 8 + tid] = hlast[tid]; // h_f
    }
}

// ---------------- launch ----------------
extern "C" void kernel_launch(void* const* d_in, const int* in_sizes, int n_in,
                              void* d_out, int out_size, void* d_ws, size_t ws_size,
                              hipStream_t stream) {
    const float* x   = (const float*)d_in[0];
    const float* c0  = (const float*)d_in[1];
    const float* h0  = (const float*)d_in[2];
    const float* Wi  = (const float*)d_in[3];
    const float* Wh  = (const float*)d_in[4];
    const float* bia = (const float*)d_in[5];
    float* out = (float*)d_out;

    char* base = (char*)d_ws;
    float* Y = (float*)base;                                  // 128 MiB
    base += (size_t)T_STEPS * NG * sizeof(float);
    unsigned* ctr = (unsigned*)base;                          // 512 B
    base += 8 * CTR_STRIDE * sizeof(unsigned);
    uint2* recs = (uint2*)base;                               // 32 KiB

    const int initN = 8 * CTR_STRIDE + 2 * NREC;
    hipLaunchKernelGGL(init_ws4, dim3((initN + 511) / 512), dim3(512), 0, stream,
                       h0, ctr, recs);
    hipLaunchKernelGGL(gemm_xwi, dim3(NG / 64, T_STEPS / 64), dim3(256), 0, stream,
                       x, Wi, bia, Y);

    void* args[] = { (void*)&Y, (void*)&c0, (void*)&Wh,
                     (void*)&recs, (void*)&ctr, (void*)&out };
    (void)hipLaunchCooperativeKernel((const void*)lstm_persistent, dim3(256), dim3(512),
                                     args, 0, stream);
}